// Round 14
// baseline (18.842 us; speedup 1.0000x reference)
//
#include <hip/hip_runtime.h>
#include <math.h>

// Realspace Ewald: pot = 2 * sum_{i<j} q_i q_j erf(d_ij/sqrt(2))/d_ij * NORM/(4pi)
// N=6144. R14: ONE transcendental per pair. Identity: erf(d/sqrt2)/d =
// rsq(t + V(t)), t=d^2, V = t(1-erf^2)/erf^2 -- smooth on [0,12], ->0 beyond.
// V approximated by deg-8 Newton interpolation on Chebyshev nodes of [0,12]
// (|dV|<=7e-4 -> |dw| = w^3*dV/2 <= 2e-4; tail via s=min(t,12), err<=1.5e-4).
// Removes v_rcp (trans ~20cyc each, 75% of R12 inner cost) and shortens the
// dependency chain (poly subs all independent; rsq is the only serial trans).
// Packed fp32 (2 i/lane), 512i x 16j blocks (R12 geometry, best so far).

#if __has_builtin(__builtin_amdgcn_rsqf)
#define FRSQ(x) __builtin_amdgcn_rsqf(x)
#else
#define FRSQ(x) rsqrtf(x)
#endif

typedef float vf2 __attribute__((ext_vector_type(2)));

__device__ __forceinline__ vf2 vfma(vf2 a, vf2 b, vf2 c) {
  return __builtin_elementwise_fma(a, b, c);
}

// Newton-form coefficients for V(s) on [0,12] (Chebyshev nodes):
// V = C0 + s*(C1 + (s-X1)*(C2 + (s-X2)*(C3 + (s-X3)*(C4 + (s-X4)*(C5 +
//     (s-X5)*(C6 + (s-X6)*(C7 + (s-X7)*C8)))))))
#define XN1 0.4567f
#define XN2 1.7574f
#define XN3 3.7039f
#define XN4 6.0f
#define XN5 8.2961f
#define XN6 10.2426f
#define XN7 11.5433f
#define C0 1.57080f
#define C1 -0.45266f
#define C2 0.04933f
#define C3 -0.0021410f
#define C4 -0.0000567f
#define C5 1.397e-5f
#define C6 -9.66e-7f
#define C7 2.37e-8f
#define C8 1.71e-9f

template <bool CHECK>
__device__ __forceinline__ void pair2_body(const float4 v, int jj, int i0,
                                           vf2 xi, vf2 yi, vf2 zi, vf2& acc) {
  vf2 dx = xi - v.x, dy = yi - v.y, dz = zi - v.z;
  vf2 t = vfma(dx, dx, vfma(dy, dy, dz * dz));
  vf2 qk = {v.w, v.w};
  if (CHECK) {
    bool t0 = (jj > i0);
    bool t1 = (jj > i0 + 64);
    qk.x = t0 ? qk.x : 0.0f;  // w is finite even at t=0 now; only mask q
    qk.y = t1 ? qk.y : 0.0f;
  }
  vf2 s = __builtin_elementwise_min(t, (vf2){12.f, 12.f});
  // independent subtracts (issue-parallel), then nested fma chain
  vf2 s1 = s - XN1, s2 = s - XN2, s3 = s - XN3, s4 = s - XN4;
  vf2 s5 = s - XN5, s6 = s - XN6, s7 = s - XN7;
  vf2 p = vfma(s7, (vf2){C8, C8}, (vf2){C7, C7});
  p = vfma(s6, p, (vf2){C6, C6});
  p = vfma(s5, p, (vf2){C5, C5});
  p = vfma(s4, p, (vf2){C4, C4});
  p = vfma(s3, p, (vf2){C3, C3});
  p = vfma(s2, p, (vf2){C2, C2});
  p = vfma(s1, p, (vf2){C1, C1});
  vf2 V = vfma(s, p, (vf2){C0, C0});  // V(s)
  vf2 u = t + V;                      // t + V  (t, not s: tail exact-ish)
  vf2 w;
  w.x = FRSQ(u.x);
  w.y = FRSQ(u.y);  // w = erf(d/sqrt2)/d
  acc = vfma(qk, w, acc);
}

template <bool CHECK>
__device__ __forceinline__ vf2 tile_sum(const float4* __restrict__ tile,
                                        int jbeg, int i0, vf2 xi, vf2 yi,
                                        vf2 zi) {
  // 4 accumulator chains: (i0,i1) packed x (even k, odd k)
  vf2 a0 = {0.f, 0.f}, a1 = {0.f, 0.f};
#pragma unroll
  for (int k = 0; k < 16; k += 2) {
    pair2_body<CHECK>(tile[k], jbeg + k, i0, xi, yi, zi, a0);
    pair2_body<CHECK>(tile[k + 1], jbeg + k + 1, i0, xi, yi, zi, a1);
  }
  return a0 + a1;
}

__global__ __launch_bounds__(256) void ewald_tri(
    const float* __restrict__ q, const float* __restrict__ r,
    float* __restrict__ partial, int n) {
  const int tid = threadIdx.x;
  const int bid = blockIdx.x;
  const int lane = tid & 63;
  const int wid = tid >> 6;
  const int jslices = (n + 15) >> 4;  // 16-wide j-slices

  // invert bid -> (ib, js): active js for 512-wide i-block ib: [32*ib, jslices)
  int ib = 0, cum = 0;
  while (true) {
    int c = jslices - 32 * ib;
    if (c <= 0 || cum + c > bid) break;
    cum += c;
    ++ib;
  }
  const int js = 32 * ib + (bid - cum);

  const int ibeg = ib << 9;  // 512-wide i-block
  const int jbeg = js << 4;  // 16-wide j-tile
  const bool pure_above = (jbeg >= ibeg + 512);

  // stage the 16-particle j-tile once (256B)
  __shared__ float4 tile[16];
  if (tid < 16) {
    int j = jbeg + tid;
    float4 v = make_float4(1e10f, 1e10f, 1e10f, 0.f);
    if (j < n) v = make_float4(r[3 * j], r[3 * j + 1], r[3 * j + 2], q[j]);
    tile[tid] = v;
  }

  // wave wid owns i-strip [ibeg+128*wid, +128); lane handles i0 and i0+64
  const int i0 = ibeg + (wid << 7) + lane;
  const int i1 = i0 + 64;
  float qi0 = 0.f, qi1 = 0.f;
  vf2 xi = {1e10f, 1e10f}, yi = {1e10f, 1e10f}, zi = {1e10f, 1e10f};
  if (i0 < n) {
    qi0 = q[i0];
    xi.x = r[3 * i0];
    yi.x = r[3 * i0 + 1];
    zi.x = r[3 * i0 + 2];
  }
  if (i1 < n) {
    qi1 = q[i1];
    xi.y = r[3 * i1];
    yi.y = r[3 * i1 + 1];
    zi.y = r[3 * i1 + 2];
  }
  __syncthreads();

  vf2 s2;
  if (pure_above)
    s2 = tile_sum<false>(tile, jbeg, i0, xi, yi, zi);
  else
    s2 = tile_sum<true>(tile, jbeg, i0, xi, yi, zi);
  float acc = fmaf(qi0, s2.x, qi1 * s2.y);

  // deterministic block reduce: wave shfl, then cross-wave via LDS
  for (int m = 32; m > 0; m >>= 1) acc += __shfl_xor(acc, m, 64);
  __shared__ float wsum[4];
  if (lane == 0) wsum[wid] = acc;
  __syncthreads();
  if (tid == 0)
    partial[bid] = (wsum[0] + wsum[1]) + (wsum[2] + wsum[3]);
}

__global__ __launch_bounds__(1024) void reduce_partials(
    const float* __restrict__ partial, float* __restrict__ out, int np,
    float scale) {
  const int tid = threadIdx.x;
  float acc = 0.f;
  for (int idx = tid; idx < np; idx += 1024) acc += partial[idx];
  for (int m = 32; m > 0; m >>= 1) acc += __shfl_xor(acc, m, 64);
  __shared__ float wsum[16];
  const int lane = tid & 63;
  const int wid = tid >> 6;
  if (lane == 0) wsum[wid] = acc;
  __syncthreads();
  if (tid == 0) {
    float s = 0.f;
    for (int w = 0; w < 16; ++w) s += wsum[w];
    out[0] = s * scale;
  }
}

extern "C" void kernel_launch(void* const* d_in, const int* in_sizes, int n_in,
                              void* d_out, int out_size, void* d_ws,
                              size_t ws_size, hipStream_t stream) {
  const float* q = (const float*)d_in[0];  // [N,1] fp32
  const float* r = (const float*)d_in[1];  // [N,3] fp32
  const int n = in_sizes[0];
  float* out = (float*)d_out;
  float* partial = (float*)d_ws;

  const int iblocks = (n + 511) / 512;
  const int jslices = (n + 15) / 16;
  int nblocks = 0;
  for (int ib = 0; ib < iblocks; ++ib) {
    int c = jslices - 32 * ib;
    if (c > 0) nblocks += c;
  }

  ewald_tri<<<nblocks, 256, 0, stream>>>(q, r, partial, n);

  // 2 (triangle symmetry) * NORM/(2pi)/2 = NORM/(2pi)
  const float scale = (float)(90.0474 / (2.0 * M_PI));
  reduce_partials<<<1, 1024, 0, stream>>>(partial, out, nblocks, scale);
}

// Round 15
// 17.154 us; speedup vs baseline: 1.0984x; 1.0984x over previous
//
#include <hip/hip_runtime.h>
#include <math.h>

// Realspace Ewald: pot = 2 * sum_{i<j} q_i q_j erf(d_ij/sqrt(2))/d_ij * NORM/(4pi)
// N=6144. erf via A&S 7.1.23 rational (absmax 0.0 since R6), Estrin, packed
// fp32 2-i-per-lane. R15: LATENCY round. Evidence: R14 delta => trans are
// cheap (~4-8cyc); issue model says main kernel ~4.8us yet it runs ~15us =>
// VALUBusy ~35%, latency-bound; VGPR=28 shows compiler can't hoist ds_reads
// or pipeline chains. Fix: 4-wide register-batched tile chunks (batched
// ds_read_b128, single drain, compute covers latency) + 4 vf2 accumulators
// (8 scalar chains). Target VGPR ~55 (keeps 8 waves/SIMD).

#if __has_builtin(__builtin_amdgcn_rsqf)
#define FRSQ(x) __builtin_amdgcn_rsqf(x)
#else
#define FRSQ(x) rsqrtf(x)
#endif
#if __has_builtin(__builtin_amdgcn_rcpf)
#define FRCP(x) __builtin_amdgcn_rcpf(x)
#else
#define FRCP(x) (1.0f / (x))
#endif

typedef float vf2 __attribute__((ext_vector_type(2)));

__device__ __forceinline__ vf2 vfma(vf2 a, vf2 b, vf2 c) {
  return __builtin_elementwise_fma(a, b, c);
}

// A&S 7.1.23 coefficients pre-multiplied by (1/sqrt(2))^k so poly is in d:
#define B1 0.19685360f
#define B2 0.11519450f
#define B3 0.00034366f
#define B4 0.01952700f

template <bool CHECK>
__device__ __forceinline__ void pair2_body(const float4 v, int jj, int i0,
                                           vf2 xi, vf2 yi, vf2 zi, vf2& acc) {
  vf2 dx = xi - v.x, dy = yi - v.y, dz = zi - v.z;
  vf2 s = vfma(dx, dx, vfma(dy, dy, dz * dz));
  vf2 qk = {v.w, v.w};
  if (CHECK) {
    bool t0 = (jj > i0);
    bool t1 = (jj > i0 + 64);
    s.x = t0 ? s.x : 1.0f;
    s.y = t1 ? s.y : 1.0f;
    qk.x = t0 ? qk.x : 0.0f;
    qk.y = t1 ? qk.y : 0.0f;
  }
  vf2 ri;
  ri.x = FRSQ(s.x);
  ri.y = FRSQ(s.y);
  // Estrin: poly = (1 + B2 s + B4 s^2) + d*(B1 + B3 s); E,O overlap rsq latency
  vf2 E = vfma(vfma((vf2){B4, B4}, s, (vf2){B2, B2}), s, (vf2){1.f, 1.f});
  vf2 O = vfma((vf2){B3, B3}, s, (vf2){B1, B1});
  vf2 dd = s * ri;
  vf2 p = vfma(dd, O, E);
  vf2 y;
  y.x = FRCP(p.x);
  y.y = FRCP(p.y);
  vf2 y2 = y * y;
  vf2 y4 = y2 * y2;
  vf2 w = vfma(-y4, ri, ri);  // erf(d/sqrt2)/d
  acc = vfma(qk, w, acc);
}

template <bool CHECK>
__device__ __forceinline__ vf2 tile_sum(const float4* __restrict__ tile,
                                        int jbeg, int i0, vf2 xi, vf2 yi,
                                        vf2 zi) {
  // 4 vf2 accumulators = 8 independent scalar chains
  vf2 a0 = {0.f, 0.f}, a1 = {0.f, 0.f}, a2 = {0.f, 0.f}, a3 = {0.f, 0.f};
#pragma unroll
  for (int kb = 0; kb < 16; kb += 4) {
    // batch 4 ds_read_b128 into named registers -> one lgkm drain, then
    // ~4x76cyc of compute fully covers LDS latency
    float4 t0 = tile[kb + 0];
    float4 t1 = tile[kb + 1];
    float4 t2 = tile[kb + 2];
    float4 t3 = tile[kb + 3];
    pair2_body<CHECK>(t0, jbeg + kb + 0, i0, xi, yi, zi, a0);
    pair2_body<CHECK>(t1, jbeg + kb + 1, i0, xi, yi, zi, a1);
    pair2_body<CHECK>(t2, jbeg + kb + 2, i0, xi, yi, zi, a2);
    pair2_body<CHECK>(t3, jbeg + kb + 3, i0, xi, yi, zi, a3);
  }
  return (a0 + a1) + (a2 + a3);
}

__global__ __launch_bounds__(256) void ewald_tri(
    const float* __restrict__ q, const float* __restrict__ r,
    float* __restrict__ partial, int n) {
  const int tid = threadIdx.x;
  const int bid = blockIdx.x;
  const int lane = tid & 63;
  const int wid = tid >> 6;
  const int jslices = (n + 15) >> 4;  // 16-wide j-slices

  // invert bid -> (ib, js): active js for 512-wide i-block ib: [32*ib, jslices)
  int ib = 0, cum = 0;
  while (true) {
    int c = jslices - 32 * ib;
    if (c <= 0 || cum + c > bid) break;
    cum += c;
    ++ib;
  }
  const int js = 32 * ib + (bid - cum);

  const int ibeg = ib << 9;  // 512-wide i-block
  const int jbeg = js << 4;  // 16-wide j-tile
  const bool pure_above = (jbeg >= ibeg + 512);

  // stage the 16-particle j-tile once (256B)
  __shared__ float4 tile[16];
  if (tid < 16) {
    int j = jbeg + tid;
    float4 v = make_float4(1e10f, 1e10f, 1e10f, 0.f);
    if (j < n) v = make_float4(r[3 * j], r[3 * j + 1], r[3 * j + 2], q[j]);
    tile[tid] = v;
  }

  // wave wid owns i-strip [ibeg+128*wid, +128); lane handles i0 and i0+64
  const int i0 = ibeg + (wid << 7) + lane;
  const int i1 = i0 + 64;
  float qi0 = 0.f, qi1 = 0.f;
  vf2 xi = {1e10f, 1e10f}, yi = {1e10f, 1e10f}, zi = {1e10f, 1e10f};
  if (i0 < n) {
    qi0 = q[i0];
    xi.x = r[3 * i0];
    yi.x = r[3 * i0 + 1];
    zi.x = r[3 * i0 + 2];
  }
  if (i1 < n) {
    qi1 = q[i1];
    xi.y = r[3 * i1];
    yi.y = r[3 * i1 + 1];
    zi.y = r[3 * i1 + 2];
  }
  __syncthreads();

  vf2 s2;
  if (pure_above)
    s2 = tile_sum<false>(tile, jbeg, i0, xi, yi, zi);
  else
    s2 = tile_sum<true>(tile, jbeg, i0, xi, yi, zi);
  float acc = fmaf(qi0, s2.x, qi1 * s2.y);

  // deterministic block reduce: wave shfl, then cross-wave via LDS
  for (int m = 32; m > 0; m >>= 1) acc += __shfl_xor(acc, m, 64);
  __shared__ float wsum[4];
  if (lane == 0) wsum[wid] = acc;
  __syncthreads();
  if (tid == 0)
    partial[bid] = (wsum[0] + wsum[1]) + (wsum[2] + wsum[3]);
}

__global__ __launch_bounds__(1024) void reduce_partials(
    const float* __restrict__ partial, float* __restrict__ out, int np,
    float scale) {
  const int tid = threadIdx.x;
  float acc = 0.f;
  for (int idx = tid; idx < np; idx += 1024) acc += partial[idx];
  for (int m = 32; m > 0; m >>= 1) acc += __shfl_xor(acc, m, 64);
  __shared__ float wsum[16];
  const int lane = tid & 63;
  const int wid = tid >> 6;
  if (lane == 0) wsum[wid] = acc;
  __syncthreads();
  if (tid == 0) {
    float s = 0.f;
    for (int w = 0; w < 16; ++w) s += wsum[w];
    out[0] = s * scale;
  }
}

extern "C" void kernel_launch(void* const* d_in, const int* in_sizes, int n_in,
                              void* d_out, int out_size, void* d_ws,
                              size_t ws_size, hipStream_t stream) {
  const float* q = (const float*)d_in[0];  // [N,1] fp32
  const float* r = (const float*)d_in[1];  // [N,3] fp32
  const int n = in_sizes[0];
  float* out = (float*)d_out;
  float* partial = (float*)d_ws;

  const int iblocks = (n + 511) / 512;
  const int jslices = (n + 15) / 16;
  int nblocks = 0;
  for (int ib = 0; ib < iblocks; ++ib) {
    int c = jslices - 32 * ib;
    if (c > 0) nblocks += c;
  }

  ewald_tri<<<nblocks, 256, 0, stream>>>(q, r, partial, n);

  // 2 (triangle symmetry) * NORM/(2pi)/2 = NORM/(2pi)
  const float scale = (float)(90.0474 / (2.0 * M_PI));
  reduce_partials<<<1, 1024, 0, stream>>>(partial, out, nblocks, scale);
}